// Round 1
// baseline (16037.595 us; speedup 1.0000x reference)
//
#include <hip/hip_runtime.h>
#include <cstdint>
#include <cstddef>

#define T_LEN 512
#define B_SZ  64
#define E_SZ  256
#define H_SZ  256

__device__ __forceinline__ float sigf(float x) { return 1.0f / (1.0f + expf(-x)); }

// ---------------------------------------------------------------------------
// K1: fused embedding-gather + BiLSTM recurrence.
// grid = 256 blocks x 512 threads. block -> (d, batch-group of 8, h-slice of 16).
// Weights (Wih, Whh rows for this slice) live in registers (32+32 f32/thread).
// Per-step inter-WG exchange of h via global memory + per-group flags
// (agent-scope atomics; per-XCD L2 non-coherence handled by release/acquire).
// ---------------------------------------------------------------------------
__global__ __launch_bounds__(512) void lstm_kernel(
    const int* __restrict__ sent,
    const float* __restrict__ emb,
    const float* __restrict__ Wih_f, const float* __restrict__ Whh_f, const float* __restrict__ b_f,
    const float* __restrict__ Wih_b, const float* __restrict__ Whh_b, const float* __restrict__ b_b,
    float* __restrict__ h_all,   // [2][513][64][256]
    int* __restrict__ flags)     // [16][512][16]
{
    const int wg  = blockIdx.x;
    const int d   = wg >> 7;          // direction
    const int g_b = (wg >> 4) & 7;    // batch group (8 b each)
    const int s   = wg & 15;          // h-slice (16 h-indices)
    const int b0  = g_b * 8;
    const int tid = threadIdx.x;
    const int w   = tid >> 6;         // wave 0..7
    const int l   = tid & 63;
    const int rh  = l >> 3;           // 0..7
    const int c   = l & 7;            // j-chunk 0..7 (32 j each)
    const int r_loc = 8 * w + rh;     // 0..63 local gate-row
    const int gate  = r_loc >> 4;     // 0..3 (i,f,g,o)
    const int h_loc = r_loc & 15;     // 0..15
    const int row   = gate * 256 + s * 16 + h_loc;  // global gate row

    const float* Wih = d ? Wih_b : Wih_f;
    const float* Whh = d ? Whh_b : Whh_f;
    const float* bv  = d ? b_b   : b_f;

    __shared__ __align__(16) int   tok[8][T_LEN];     // 16 KB
    __shared__ __align__(16) float xl[8][8][44];      // padded: stride 44 -> conflict-free b128
    __shared__ __align__(16) float hl[8][8][44];
    __shared__ __align__(16) float gst[4][16][8];     // [gate][h_loc][b]

    // ---- stationary weights in registers ----
    float wih[32], whh[32];
#pragma unroll
    for (int k = 0; k < 8; ++k) {
        float4 a = *(const float4*)(Wih + (size_t)row * 256 + 32 * c + 4 * k);
        wih[4*k+0] = a.x; wih[4*k+1] = a.y; wih[4*k+2] = a.z; wih[4*k+3] = a.w;
        float4 b4 = *(const float4*)(Whh + (size_t)row * 256 + 32 * c + 4 * k);
        whh[4*k+0] = b4.x; whh[4*k+1] = b4.y; whh[4*k+2] = b4.z; whh[4*k+3] = b4.w;
    }
    const float bias_r = bv[row];

    // ---- tokens for this batch group (contiguous 4096 ints) ----
    {
        const int4* sp = (const int4*)(sent + (size_t)b0 * T_LEN);
        int4* tp = (int4*)(&tok[0][0]);
        tp[tid]       = sp[tid];
        tp[tid + 512] = sp[tid + 512];
    }
    __syncthreads();

    // assembly-thread state (tid < 128): (a_b, a_h) fixed -> c in register
    const int a_b = tid >> 4;   // 0..7
    const int a_h = tid & 15;   // 0..15
    float c_reg = 0.0f;

    float* h_base = h_all + (size_t)d * 513 * B_SZ * H_SZ;
    int*   flg_g  = flags + (size_t)(d * 8 + g_b) * T_LEN * 16;

    // first x prefetch (wave w stages batch element b0+w)
    {
        int t_in0 = d ? (T_LEN - 1) : 0;
        // nothing; loaded below
        (void)t_in0;
    }
    int t_in_first = d ? (T_LEN - 1) : 0;
    float4 xpref = *(const float4*)(emb + (size_t)tok[w][t_in_first] * E_SZ + 4 * l);

    for (int t = 0; t < T_LEN; ++t) {
        // stage x(t) (uses xpref), then prefetch x(t+1)
        *(float4*)&xl[w][l >> 3][4 * (l & 7)] = xpref;
        {
            int tn = (t + 1 < T_LEN) ? (t + 1) : t;
            int t_in_n = d ? (T_LEN - 1 - tn) : tn;
            xpref = *(const float4*)(emb + (size_t)tok[w][t_in_n] * E_SZ + 4 * l);
        }
        __syncthreads();   // xl ready

        // ---- phase A: p += Wih_slice . x  (no cross-WG dependency) ----
        float p[8] = {0.f, 0.f, 0.f, 0.f, 0.f, 0.f, 0.f, 0.f};
#pragma unroll
        for (int blk = 0; blk < 8; ++blk) {
#pragma unroll
            for (int b = 0; b < 8; ++b) {
                float4 v = *(const float4*)&xl[b][c][4 * blk];
                p[b] += wih[4*blk+0] * v.x + wih[4*blk+1] * v.y
                      + wih[4*blk+2] * v.z + wih[4*blk+3] * v.w;
            }
        }

        // ---- wait for h(t) from the 15 peer slices (group flags) ----
        if (t > 0 && w == 0) {
            const int* fp = flg_g + (size_t)(t - 1) * 16;
            int spins = 0;
            for (;;) {
                int v = (l < 16) ? __hip_atomic_load(fp + l, __ATOMIC_RELAXED,
                                                     __HIP_MEMORY_SCOPE_AGENT) : 1;
                if (__all(v != 0)) break;
                if (++spins > 1000000) break;   // bail: fail instead of hang
            }
            __threadfence();  // acquire: invalidate stale L1/L2
        }
        __syncthreads();

        // ---- load + stage h(t) ----
        {
            float4 hv = *(const float4*)(h_base + ((size_t)t * B_SZ + b0 + w) * H_SZ + 4 * l);
            *(float4*)&hl[w][l >> 3][4 * (l & 7)] = hv;
        }
        __syncthreads();   // hl ready

        // ---- phase B: p += Whh_slice . h ----
#pragma unroll
        for (int blk = 0; blk < 8; ++blk) {
#pragma unroll
            for (int b = 0; b < 8; ++b) {
                float4 v = *(const float4*)&hl[b][c][4 * blk];
                p[b] += whh[4*blk+0] * v.x + whh[4*blk+1] * v.y
                      + whh[4*blk+2] * v.z + whh[4*blk+3] * v.w;
            }
        }

        // ---- butterfly over the 8 j-chunk lanes ----
#pragma unroll
        for (int m = 1; m <= 4; m <<= 1) {
#pragma unroll
            for (int b = 0; b < 8; ++b) p[b] += __shfl_xor(p[b], m, 64);
        }
        // lane keeps b == c
        float q0 = (c & 1) ? p[1] : p[0];
        float q1 = (c & 1) ? p[3] : p[2];
        float q2 = (c & 1) ? p[5] : p[4];
        float q3 = (c & 1) ? p[7] : p[6];
        float r0 = (c & 2) ? q1 : q0;
        float r1 = (c & 2) ? q3 : q2;
        float gv = ((c & 4) ? r1 : r0) + bias_r;
        gst[gate][h_loc][c] = gv;
        __syncthreads();   // gates ready

        // ---- gate assembly + h store (tid < 128) ----
        if (tid < 128) {
            float iv = gst[0][a_h][a_b];
            float fv = gst[1][a_h][a_b];
            float gg = gst[2][a_h][a_b];
            float ov = gst[3][a_h][a_b];
            c_reg = sigf(fv) * c_reg + sigf(iv) * tanhf(gg);
            float hn = sigf(ov) * tanhf(c_reg);
            __hip_atomic_store(h_base + ((size_t)(t + 1) * B_SZ + b0 + a_b) * H_SZ + s * 16 + a_h,
                               hn, __ATOMIC_RELAXED, __HIP_MEMORY_SCOPE_AGENT);
        }
        __syncthreads();   // h stores drained (vmcnt) before publishing

        if (tid == 0) {
            __hip_atomic_store(flg_g + (size_t)t * 16 + s, 1,
                               __ATOMIC_RELEASE, __HIP_MEMORY_SCOPE_AGENT);
        }
    }
}

// ---------------------------------------------------------------------------
// K2: logits[b][t][k] = b_out[k] + h_f(t).Wout[k][0:256] + h_b(t).Wout[k][256:512]
// thread per (b,t) row; Wout accesses are wave-uniform (scalar-cached).
// ---------------------------------------------------------------------------
__global__ __launch_bounds__(256) void logits_kernel(
    const float* __restrict__ h_all, const float* __restrict__ W_out,
    const float* __restrict__ b_out, float* __restrict__ logits)
{
    int g = blockIdx.x * 256 + threadIdx.x;   // 0..32767
    int b = g >> 9;
    int t = g & 511;
    const float* hf = h_all + ((size_t)(t + 1) * B_SZ + b) * H_SZ;
    const float* hb = h_all + (size_t)513 * B_SZ * H_SZ + ((size_t)(512 - t) * B_SZ + b) * H_SZ;
    float acc[10];
#pragma unroll
    for (int k = 0; k < 10; ++k) acc[k] = b_out[k];
    for (int j = 0; j < 256; j += 4) {
        float4 a  = *(const float4*)(hf + j);
        float4 bb = *(const float4*)(hb + j);
#pragma unroll
        for (int k = 0; k < 10; ++k) {
            float4 w0 = *(const float4*)(W_out + (size_t)k * 512 + j);
            float4 w1 = *(const float4*)(W_out + (size_t)k * 512 + 256 + j);
            acc[k] += a.x * w0.x + a.y * w0.y + a.z * w0.z + a.w * w0.w
                    + bb.x * w1.x + bb.y * w1.y + bb.z * w1.z + bb.w * w1.w;
        }
    }
    float* lp = logits + ((size_t)b * 512 + t) * 10;
#pragma unroll
    for (int k = 0; k < 10; ++k) lp[k] = acc[k];
}

// ---------------------------------------------------------------------------
// K3: Viterbi per batch element. Block = 1 wave; trellis in lanes 0..9,
// backpointers + logits staged in LDS; serial backtrack from LDS.
// ---------------------------------------------------------------------------
__global__ __launch_bounds__(64) void viterbi_kernel(
    const float* __restrict__ logits, const float* __restrict__ trans,
    float* __restrict__ out)
{
    int b = blockIdx.x;
    int l = threadIdx.x;
    __shared__ __align__(16) float ll[512][10];
    __shared__ int   bp[512][10];
    __shared__ float path[512];

    const float* lp = logits + (size_t)b * 5120;
    for (int i = l; i < 5120; i += 64) ((float*)ll)[i] = lp[i];

    int j = (l < 10) ? l : 9;
    float tr[10];
#pragma unroll
    for (int i = 0; i < 10; ++i) tr[i] = trans[i * 10 + j];
    __syncthreads();

    float trellis = ll[0][j];
    for (int t = 1; t < 512; ++t) {
        float best = -3.0e30f; int arg = 0;
#pragma unroll
        for (int i = 0; i < 10; ++i) {
            float ti = __shfl(trellis, i, 64);
            float cand = ti + tr[i];
            bool gt = cand > best;           // strict > keeps first max (matches argmax)
            best = gt ? cand : best;
            arg  = gt ? i : arg;
        }
        if (l < 10) bp[t][l] = arg;
        trellis = ll[t][j] + best;
    }

    float best = -3.0e30f; int arg = 0;
#pragma unroll
    for (int i = 0; i < 10; ++i) {
        float ti = __shfl(trellis, i, 64);
        bool gt = ti > best;
        best = gt ? ti : best;
        arg  = gt ? i : arg;
    }
    __syncthreads();
    if (l == 0) {
        out[b] = best;
        int tag = arg;
        path[511] = (float)tag;
        for (int t2 = 510; t2 >= 0; --t2) {
            tag = bp[t2 + 1][tag];
            path[t2] = (float)tag;
        }
    }
    __syncthreads();
    float* po = out + 64 + (size_t)b * 512;
    for (int i = l; i < 512; i += 64) po[i] = path[i];
}

// ---------------------------------------------------------------------------
extern "C" void kernel_launch(void* const* d_in, const int* in_sizes, int n_in,
                              void* d_out, int out_size, void* d_ws, size_t ws_size,
                              hipStream_t stream)
{
    (void)in_sizes; (void)n_in; (void)out_size; (void)ws_size;
    const int*   sent  = (const int*)d_in[0];
    // d_in[1] = lengths (unused by the reference computation)
    const float* emb   = (const float*)d_in[2];
    const float* Wih_f = (const float*)d_in[3];
    const float* Whh_f = (const float*)d_in[4];
    const float* b_f   = (const float*)d_in[5];
    const float* Wih_b = (const float*)d_in[6];
    const float* Whh_b = (const float*)d_in[7];
    const float* b_b   = (const float*)d_in[8];
    const float* W_out = (const float*)d_in[9];
    const float* b_out = (const float*)d_in[10];
    const float* trans = (const float*)d_in[11];
    float* out = (float*)d_out;

    char* ws = (char*)d_ws;
    float* h_all = (float*)ws;                               // [2][513][64][256] f32
    const size_t h_bytes = (size_t)2 * 513 * B_SZ * H_SZ * 4;  // 67,239,936
    int*   flags  = (int*)(ws + h_bytes);                    // [16][512][16] i32 = 512 KB
    float* logits = (float*)(ws + h_bytes + 524288);         // [64][512][10] f32

    // zero initial h for both directions + all flags (ws is poisoned each call)
    hipMemsetAsync(h_all, 0, (size_t)B_SZ * H_SZ * 4, stream);
    hipMemsetAsync((char*)h_all + (size_t)513 * B_SZ * H_SZ * 4, 0,
                   (size_t)B_SZ * H_SZ * 4, stream);
    hipMemsetAsync(flags, 0, 524288, stream);

    hipLaunchKernelGGL(lstm_kernel, dim3(256), dim3(512), 0, stream,
                       sent, emb, Wih_f, Whh_f, b_f, Wih_b, Whh_b, b_b, h_all, flags);
    hipLaunchKernelGGL(logits_kernel, dim3(128), dim3(256), 0, stream,
                       h_all, W_out, b_out, logits);
    hipLaunchKernelGGL(viterbi_kernel, dim3(64), dim3(64), 0, stream,
                       logits, trans, out);
}

// Round 2
// 8676.553 us; speedup vs baseline: 1.8484x; 1.8484x over previous
//
#include <hip/hip_runtime.h>
#include <cstdint>
#include <cstddef>

#define T_LEN 512
#define B_SZ  64
#define E_SZ  256
#define H_SZ  256

__device__ __forceinline__ float sigf(float x) { return 1.0f / (1.0f + expf(-x)); }

// LLC-coherent (agent-scope, cache-bypass) 16B load as two 8B atomic loads.
__device__ __forceinline__ float4 agent_load_f4(const float* p) {
    unsigned long long a = __hip_atomic_load((const unsigned long long*)p,
                                             __ATOMIC_RELAXED, __HIP_MEMORY_SCOPE_AGENT);
    unsigned long long b = __hip_atomic_load((const unsigned long long*)p + 1,
                                             __ATOMIC_RELAXED, __HIP_MEMORY_SCOPE_AGENT);
    union { unsigned long long u[2]; float4 f; } r;
    r.u[0] = a; r.u[1] = b;
    return r.f;
}

// ---------------------------------------------------------------------------
// K1: fused embedding-gather + BiLSTM recurrence.
// grid = 256 blocks x 512 threads. block -> (d, batch-group of 8, h-slice of 16).
// Weights (Wih, Whh rows for this slice) live in registers (32+32 f32/thread).
// Cross-WG h exchange: relaxed AGENT-scope atomics only (per-access L2 bypass,
// coherent at LLC) -- NO fences, so no buffer_inv/buffer_wbl2 L2 thrash.
// Ordering: s_waitcnt vmcnt(0) before s_barrier (compiler-emitted) drains the
// write-through h stores before tid0 bumps the per-(group,t) counter.
// ---------------------------------------------------------------------------
__global__ __launch_bounds__(512) void lstm_kernel(
    const int* __restrict__ sent,
    const float* __restrict__ emb,
    const float* __restrict__ Wih_f, const float* __restrict__ Whh_f, const float* __restrict__ b_f,
    const float* __restrict__ Wih_b, const float* __restrict__ Whh_b, const float* __restrict__ b_b,
    float* __restrict__ h_all,   // [2][513][64][256]
    int* __restrict__ cnt)       // [16][512]
{
    const int wg  = blockIdx.x;
    const int d   = wg >> 7;          // direction
    const int g_b = (wg >> 4) & 7;    // batch group (8 b each)
    const int s   = wg & 15;          // h-slice (16 h-indices)
    const int b0  = g_b * 8;
    const int tid = threadIdx.x;
    const int w   = tid >> 6;         // wave 0..7
    const int l   = tid & 63;
    const int rh  = l >> 3;           // 0..7
    const int c   = l & 7;            // j-chunk 0..7 (32 j each)
    const int r_loc = 8 * w + rh;     // 0..63 local gate-row
    const int gate  = r_loc >> 4;     // 0..3 (i,f,g,o)
    const int h_loc = r_loc & 15;     // 0..15
    const int row   = gate * 256 + s * 16 + h_loc;  // global gate row

    const float* Wih = d ? Wih_b : Wih_f;
    const float* Whh = d ? Whh_b : Whh_f;
    const float* bv  = d ? b_b   : b_f;

    __shared__ __align__(16) int   tok[8][T_LEN];     // 16 KB
    __shared__ __align__(16) float xl[8][8][44];      // padded stride 44: conflict-free b128
    __shared__ __align__(16) float hl[8][8][44];
    __shared__ __align__(16) float gst[4][16][8];     // [gate][h_loc][b]

    // ---- stationary weights in registers ----
    float wih[32], whh[32];
#pragma unroll
    for (int k = 0; k < 8; ++k) {
        float4 a = *(const float4*)(Wih + (size_t)row * 256 + 32 * c + 4 * k);
        wih[4*k+0] = a.x; wih[4*k+1] = a.y; wih[4*k+2] = a.z; wih[4*k+3] = a.w;
        float4 b4 = *(const float4*)(Whh + (size_t)row * 256 + 32 * c + 4 * k);
        whh[4*k+0] = b4.x; whh[4*k+1] = b4.y; whh[4*k+2] = b4.z; whh[4*k+3] = b4.w;
    }
    const float bias_r = bv[row];

    // ---- tokens for this batch group (contiguous 4096 ints) ----
    {
        const int4* sp = (const int4*)(sent + (size_t)b0 * T_LEN);
        int4* tp = (int4*)(&tok[0][0]);
        tp[tid]       = sp[tid];
        tp[tid + 512] = sp[tid + 512];
    }
    __syncthreads();

    // assembly-thread state (tid < 128): (a_b, a_h) fixed -> c-state in register
    const int a_b = tid >> 4;   // 0..7
    const int a_h = tid & 15;   // 0..15
    float c_reg = 0.0f;

    float* h_base = h_all + (size_t)d * 513 * B_SZ * H_SZ;
    int*   cnt_g  = cnt + (size_t)(d * 8 + g_b) * T_LEN;

    int t_in_first = d ? (T_LEN - 1) : 0;
    float4 xpref = *(const float4*)(emb + (size_t)tok[w][t_in_first] * E_SZ + 4 * l);

    for (int t = 0; t < T_LEN; ++t) {
        // stage x(t) (uses xpref), then prefetch x(t+1)
        *(float4*)&xl[w][l >> 3][4 * (l & 7)] = xpref;
        {
            int tn = (t + 1 < T_LEN) ? (t + 1) : t;
            int t_in_n = d ? (T_LEN - 1 - tn) : tn;
            xpref = *(const float4*)(emb + (size_t)tok[w][t_in_n] * E_SZ + 4 * l);
        }
        __syncthreads();   // (1) xl ready (also: prev-iter xl/gst reads complete)

        // ---- phase A: p += Wih_slice . x  (no cross-WG dependency) ----
        float p[8] = {0.f, 0.f, 0.f, 0.f, 0.f, 0.f, 0.f, 0.f};
#pragma unroll
        for (int blk = 0; blk < 8; ++blk) {
#pragma unroll
            for (int b = 0; b < 8; ++b) {
                float4 v = *(const float4*)&xl[b][c][4 * blk];
                p[b] += wih[4*blk+0] * v.x + wih[4*blk+1] * v.y
                      + wih[4*blk+2] * v.z + wih[4*blk+3] * v.w;
            }
        }

        // ---- wait for h(t): poll the group's arrival counter (per-wave, no fence) ----
        if (t > 0) {
            int spins = 0;
            while (__hip_atomic_load(cnt_g + (t - 1), __ATOMIC_RELAXED,
                                     __HIP_MEMORY_SCOPE_AGENT) < 16) {
                if (++spins > 3000000) break;   // bail: fail instead of hang
            }
        }

        // ---- load + stage h(t) (LLC-coherent bypass loads) ----
        {
            float4 hv = agent_load_f4(h_base + ((size_t)t * B_SZ + b0 + w) * H_SZ + 4 * l);
            *(float4*)&hl[w][l >> 3][4 * (l & 7)] = hv;
        }
        __syncthreads();   // (2) hl ready

        // ---- phase B: p += Whh_slice . h ----
#pragma unroll
        for (int blk = 0; blk < 8; ++blk) {
#pragma unroll
            for (int b = 0; b < 8; ++b) {
                float4 v = *(const float4*)&hl[b][c][4 * blk];
                p[b] += whh[4*blk+0] * v.x + whh[4*blk+1] * v.y
                      + whh[4*blk+2] * v.z + whh[4*blk+3] * v.w;
            }
        }

        // ---- butterfly over the 8 j-chunk lanes ----
#pragma unroll
        for (int m = 1; m <= 4; m <<= 1) {
#pragma unroll
            for (int b = 0; b < 8; ++b) p[b] += __shfl_xor(p[b], m, 64);
        }
        float q0 = (c & 1) ? p[1] : p[0];
        float q1 = (c & 1) ? p[3] : p[2];
        float q2 = (c & 1) ? p[5] : p[4];
        float q3 = (c & 1) ? p[7] : p[6];
        float r0 = (c & 2) ? q1 : q0;
        float r1 = (c & 2) ? q3 : q2;
        float gv = ((c & 4) ? r1 : r0) + bias_r;
        gst[gate][h_loc][c] = gv;
        __syncthreads();   // (3) gates ready

        // ---- gate assembly + h store (tid < 128), write-through agent stores ----
        if (tid < 128) {
            float iv = gst[0][a_h][a_b];
            float fv = gst[1][a_h][a_b];
            float gg = gst[2][a_h][a_b];
            float ov = gst[3][a_h][a_b];
            c_reg = sigf(fv) * c_reg + sigf(iv) * tanhf(gg);
            float hn = sigf(ov) * tanhf(c_reg);
            __hip_atomic_store(h_base + ((size_t)(t + 1) * B_SZ + b0 + a_b) * H_SZ + s * 16 + a_h,
                               hn, __ATOMIC_RELAXED, __HIP_MEMORY_SCOPE_AGENT);
        }
        __syncthreads();   // (4) s_waitcnt vmcnt(0) before barrier drains h stores

        if (tid == 0) {
            __hip_atomic_fetch_add(cnt_g + t, 1, __ATOMIC_RELAXED,
                                   __HIP_MEMORY_SCOPE_AGENT);
        }
    }
}

// ---------------------------------------------------------------------------
// K2: logits[b][t][k] = b_out[k] + h_f(t).Wout[k][0:256] + h_b(t).Wout[k][256:512]
// thread per (b,t), b-minor so a wave's 64 lanes cover one t (better L2 reuse).
// ---------------------------------------------------------------------------
__global__ __launch_bounds__(256) void logits_kernel(
    const float* __restrict__ h_all, const float* __restrict__ W_out,
    const float* __restrict__ b_out, float* __restrict__ logits)
{
    int g = blockIdx.x * 256 + threadIdx.x;   // 0..32767
    int b = g & 63;
    int t = g >> 6;
    const float* hf = h_all + ((size_t)(t + 1) * B_SZ + b) * H_SZ;
    const float* hb = h_all + (size_t)513 * B_SZ * H_SZ + ((size_t)(512 - t) * B_SZ + b) * H_SZ;
    float acc[10];
#pragma unroll
    for (int k = 0; k < 10; ++k) acc[k] = b_out[k];
    for (int j = 0; j < 256; j += 4) {
        float4 a  = *(const float4*)(hf + j);
        float4 bb = *(const float4*)(hb + j);
#pragma unroll
        for (int k = 0; k < 10; ++k) {
            float4 w0 = *(const float4*)(W_out + (size_t)k * 512 + j);
            float4 w1 = *(const float4*)(W_out + (size_t)k * 512 + 256 + j);
            acc[k] += a.x * w0.x + a.y * w0.y + a.z * w0.z + a.w * w0.w
                    + bb.x * w1.x + bb.y * w1.y + bb.z * w1.z + bb.w * w1.w;
        }
    }
    float* lp = logits + ((size_t)b * 512 + t) * 10;
#pragma unroll
    for (int k = 0; k < 10; ++k) lp[k] = acc[k];
}

// ---------------------------------------------------------------------------
// K3: Viterbi per batch element. Block = 1 wave; trellis in lanes 0..9,
// backpointers + logits staged in LDS; serial backtrack from LDS.
// ---------------------------------------------------------------------------
__global__ __launch_bounds__(64) void viterbi_kernel(
    const float* __restrict__ logits, const float* __restrict__ trans,
    float* __restrict__ out)
{
    int b = blockIdx.x;
    int l = threadIdx.x;
    __shared__ __align__(16) float ll[512][10];
    __shared__ int   bp[512][10];
    __shared__ float path[512];

    const float* lp = logits + (size_t)b * 5120;
    for (int i = l; i < 5120; i += 64) ((float*)ll)[i] = lp[i];

    int j = (l < 10) ? l : 9;
    float tr[10];
#pragma unroll
    for (int i = 0; i < 10; ++i) tr[i] = trans[i * 10 + j];
    __syncthreads();

    float trellis = ll[0][j];
    for (int t = 1; t < 512; ++t) {
        float best = -3.0e30f; int arg = 0;
#pragma unroll
        for (int i = 0; i < 10; ++i) {
            float ti = __shfl(trellis, i, 64);
            float cand = ti + tr[i];
            bool gt = cand > best;           // strict > keeps first max (matches argmax)
            best = gt ? cand : best;
            arg  = gt ? i : arg;
        }
        if (l < 10) bp[t][l] = arg;
        trellis = ll[t][j] + best;
    }

    float best = -3.0e30f; int arg = 0;
#pragma unroll
    for (int i = 0; i < 10; ++i) {
        float ti = __shfl(trellis, i, 64);
        bool gt = ti > best;
        best = gt ? ti : best;
        arg  = gt ? i : arg;
    }
    __syncthreads();
    if (l == 0) {
        out[b] = best;
        int tag = arg;
        path[511] = (float)tag;
        for (int t2 = 510; t2 >= 0; --t2) {
            tag = bp[t2 + 1][tag];
            path[t2] = (float)tag;
        }
    }
    __syncthreads();
    float* po = out + 64 + (size_t)b * 512;
    for (int i = l; i < 512; i += 64) po[i] = path[i];
}

// ---------------------------------------------------------------------------
extern "C" void kernel_launch(void* const* d_in, const int* in_sizes, int n_in,
                              void* d_out, int out_size, void* d_ws, size_t ws_size,
                              hipStream_t stream)
{
    (void)in_sizes; (void)n_in; (void)out_size; (void)ws_size;
    const int*   sent  = (const int*)d_in[0];
    // d_in[1] = lengths (unused by the reference computation)
    const float* emb   = (const float*)d_in[2];
    const float* Wih_f = (const float*)d_in[3];
    const float* Whh_f = (const float*)d_in[4];
    const float* b_f   = (const float*)d_in[5];
    const float* Wih_b = (const float*)d_in[6];
    const float* Whh_b = (const float*)d_in[7];
    const float* b_b   = (const float*)d_in[8];
    const float* W_out = (const float*)d_in[9];
    const float* b_out = (const float*)d_in[10];
    const float* trans = (const float*)d_in[11];
    float* out = (float*)d_out;

    char* ws = (char*)d_ws;
    float* h_all = (float*)ws;                               // [2][513][64][256] f32
    const size_t h_bytes = (size_t)2 * 513 * B_SZ * H_SZ * 4;  // 67,239,936
    int*   cnt    = (int*)(ws + h_bytes);                    // [16][512] i32 = 32 KB
    float* logits = (float*)(ws + h_bytes + 524288);         // [64][512][10] f32

    // zero initial h for both directions + all counters (ws is poisoned each call)
    hipMemsetAsync(h_all, 0, (size_t)B_SZ * H_SZ * 4, stream);
    hipMemsetAsync((char*)h_all + (size_t)513 * B_SZ * H_SZ * 4, 0,
                   (size_t)B_SZ * H_SZ * 4, stream);
    hipMemsetAsync(cnt, 0, (size_t)16 * T_LEN * 4, stream);

    hipLaunchKernelGGL(lstm_kernel, dim3(256), dim3(512), 0, stream,
                       sent, emb, Wih_f, Whh_f, b_f, Wih_b, Whh_b, b_b, h_all, cnt);
    hipLaunchKernelGGL(logits_kernel, dim3(128), dim3(256), 0, stream,
                       h_all, W_out, b_out, logits);
    hipLaunchKernelGGL(viterbi_kernel, dim3(64), dim3(64), 0, stream,
                       logits, trans, out);
}

// Round 3
// 8579.230 us; speedup vs baseline: 1.8694x; 1.0113x over previous
//
#include <hip/hip_runtime.h>
#include <cstdint>
#include <cstddef>

#define T_LEN 512
#define B_SZ  64
#define E_SZ  256
#define H_SZ  256

__device__ __forceinline__ float sigf(float x) { return 1.0f / (1.0f + expf(-x)); }

// LLC-coherent (agent-scope, cache-bypass) 16B load as two 8B atomic loads.
__device__ __forceinline__ float4 agent_load_f4(const float* p) {
    unsigned long long a = __hip_atomic_load((const unsigned long long*)p,
                                             __ATOMIC_RELAXED, __HIP_MEMORY_SCOPE_AGENT);
    unsigned long long b = __hip_atomic_load((const unsigned long long*)p + 1,
                                             __ATOMIC_RELAXED, __HIP_MEMORY_SCOPE_AGENT);
    union { unsigned long long u[2]; float4 f; } r;
    r.u[0] = a; r.u[1] = b;
    return r.f;
}

// ---------------------------------------------------------------------------
// K1: fused embedding-gather + BiLSTM recurrence.
// grid = 256 blocks x 512 threads. block -> (d, batch-group of 8, h-slice of 16).
// Weights (Wih, Whh rows for this slice) live in registers (32+32 f32/thread).
// Cross-WG h exchange: relaxed AGENT-scope accesses (L2-bypass, LLC-coherent),
// NO fences.
// Sync design (R3): per (group,t) a 64-B line of 16 store-flags.
//   - producers: ONE relaxed store each (parallel; no RMW serialization)
//   - poll line (t-1) and publish line (t) are distinct 64-B lines
//   - only wave 0 polls (lanes 0..15 -> one coalesced 64-B fabric request)
// Ordering: compiler-emitted s_waitcnt vmcnt(0) before s_barrier drains the
// write-through h stores before tid0 publishes the flag.
// ---------------------------------------------------------------------------
__global__ __launch_bounds__(512) void lstm_kernel(
    const int* __restrict__ sent,
    const float* __restrict__ emb,
    const float* __restrict__ Wih_f, const float* __restrict__ Whh_f, const float* __restrict__ b_f,
    const float* __restrict__ Wih_b, const float* __restrict__ Whh_b, const float* __restrict__ b_b,
    float* __restrict__ h_all,   // [2][513][64][256]
    int* __restrict__ flags)     // [16][512][16] -- one 64-B line per (g,t)
{
    const int wg  = blockIdx.x;
    const int d   = wg >> 7;          // direction
    const int g_b = (wg >> 4) & 7;    // batch group (8 b each)
    const int s   = wg & 15;          // h-slice (16 h-indices)
    const int b0  = g_b * 8;
    const int tid = threadIdx.x;
    const int w   = tid >> 6;         // wave 0..7
    const int l   = tid & 63;
    const int rh  = l >> 3;           // 0..7
    const int c   = l & 7;            // j-chunk 0..7 (32 j each)
    const int r_loc = 8 * w + rh;     // 0..63 local gate-row
    const int gate  = r_loc >> 4;     // 0..3 (i,f,g,o)
    const int h_loc = r_loc & 15;     // 0..15
    const int row   = gate * 256 + s * 16 + h_loc;  // global gate row

    const float* Wih = d ? Wih_b : Wih_f;
    const float* Whh = d ? Whh_b : Whh_f;
    const float* bv  = d ? b_b   : b_f;

    __shared__ __align__(16) int   tok[8][T_LEN];     // 16 KB
    __shared__ __align__(16) float xl[8][8][44];      // padded stride 44: conflict-free b128
    __shared__ __align__(16) float hl[8][8][44];
    __shared__ __align__(16) float gst[4][16][8];     // [gate][h_loc][b]

    // ---- stationary weights in registers ----
    float wih[32], whh[32];
#pragma unroll
    for (int k = 0; k < 8; ++k) {
        float4 a = *(const float4*)(Wih + (size_t)row * 256 + 32 * c + 4 * k);
        wih[4*k+0] = a.x; wih[4*k+1] = a.y; wih[4*k+2] = a.z; wih[4*k+3] = a.w;
        float4 b4 = *(const float4*)(Whh + (size_t)row * 256 + 32 * c + 4 * k);
        whh[4*k+0] = b4.x; whh[4*k+1] = b4.y; whh[4*k+2] = b4.z; whh[4*k+3] = b4.w;
    }
    const float bias_r = bv[row];

    // ---- tokens for this batch group (contiguous 4096 ints) ----
    {
        const int4* sp = (const int4*)(sent + (size_t)b0 * T_LEN);
        int4* tp = (int4*)(&tok[0][0]);
        tp[tid]       = sp[tid];
        tp[tid + 512] = sp[tid + 512];
    }
    __syncthreads();

    // assembly-thread state (tid < 128): (a_b, a_h) fixed -> c-state in register
    const int a_b = tid >> 4;   // 0..7
    const int a_h = tid & 15;   // 0..15
    float c_reg = 0.0f;

    float* h_base = h_all + (size_t)d * 513 * B_SZ * H_SZ;
    int*   flg_g  = flags + (size_t)(d * 8 + g_b) * T_LEN * 16;

    int t_in_first = d ? (T_LEN - 1) : 0;
    float4 xpref = *(const float4*)(emb + (size_t)tok[w][t_in_first] * E_SZ + 4 * l);

    for (int t = 0; t < T_LEN; ++t) {
        // stage x(t) (uses xpref), then prefetch x(t+1)
        *(float4*)&xl[w][l >> 3][4 * (l & 7)] = xpref;
        {
            int tn = (t + 1 < T_LEN) ? (t + 1) : t;
            int t_in_n = d ? (T_LEN - 1 - tn) : tn;
            xpref = *(const float4*)(emb + (size_t)tok[w][t_in_n] * E_SZ + 4 * l);
        }
        __syncthreads();   // (1) xl ready (also: prev-iter xl/gst reads complete)

        // ---- phase A: p += Wih_slice . x  (no cross-WG dependency) ----
        float p[8] = {0.f, 0.f, 0.f, 0.f, 0.f, 0.f, 0.f, 0.f};
#pragma unroll
        for (int blk = 0; blk < 8; ++blk) {
#pragma unroll
            for (int b = 0; b < 8; ++b) {
                float4 v = *(const float4*)&xl[b][c][4 * blk];
                p[b] += wih[4*blk+0] * v.x + wih[4*blk+1] * v.y
                      + wih[4*blk+2] * v.z + wih[4*blk+3] * v.w;
            }
        }

        // ---- wait for h(t): wave 0 polls the 16-flag line (one 64-B request) ----
        if (t > 0 && w == 0) {
            const int* fp = flg_g + (size_t)(t - 1) * 16;
            int spins = 0;
            for (;;) {
                int v = (l < 16) ? __hip_atomic_load(fp + l, __ATOMIC_RELAXED,
                                                     __HIP_MEMORY_SCOPE_AGENT) : 1;
                if (__all(v != 0)) break;
                if (++spins > 3000000) break;   // bail: fail instead of hang
            }
        }
        __syncthreads();   // (2) release other waves once flags observed

        // ---- load + stage h(t) (LLC-coherent bypass loads) ----
        {
            float4 hv = agent_load_f4(h_base + ((size_t)t * B_SZ + b0 + w) * H_SZ + 4 * l);
            *(float4*)&hl[w][l >> 3][4 * (l & 7)] = hv;
        }
        __syncthreads();   // (3) hl ready

        // ---- phase B: p += Whh_slice . h ----
#pragma unroll
        for (int blk = 0; blk < 8; ++blk) {
#pragma unroll
            for (int b = 0; b < 8; ++b) {
                float4 v = *(const float4*)&hl[b][c][4 * blk];
                p[b] += whh[4*blk+0] * v.x + whh[4*blk+1] * v.y
                      + whh[4*blk+2] * v.z + whh[4*blk+3] * v.w;
            }
        }

        // ---- butterfly over the 8 j-chunk lanes ----
#pragma unroll
        for (int m = 1; m <= 4; m <<= 1) {
#pragma unroll
            for (int b = 0; b < 8; ++b) p[b] += __shfl_xor(p[b], m, 64);
        }
        float q0 = (c & 1) ? p[1] : p[0];
        float q1 = (c & 1) ? p[3] : p[2];
        float q2 = (c & 1) ? p[5] : p[4];
        float q3 = (c & 1) ? p[7] : p[6];
        float r0 = (c & 2) ? q1 : q0;
        float r1 = (c & 2) ? q3 : q2;
        float gv = ((c & 4) ? r1 : r0) + bias_r;
        gst[gate][h_loc][c] = gv;
        __syncthreads();   // (4) gates ready

        // ---- gate assembly + h store (tid < 128), write-through agent stores ----
        if (tid < 128) {
            float iv = gst[0][a_h][a_b];
            float fv = gst[1][a_h][a_b];
            float gg = gst[2][a_h][a_b];
            float ov = gst[3][a_h][a_b];
            c_reg = sigf(fv) * c_reg + sigf(iv) * tanhf(gg);
            float hn = sigf(ov) * tanhf(c_reg);
            __hip_atomic_store(h_base + ((size_t)(t + 1) * B_SZ + b0 + a_b) * H_SZ + s * 16 + a_h,
                               hn, __ATOMIC_RELAXED, __HIP_MEMORY_SCOPE_AGENT);
        }
        __syncthreads();   // (5) s_waitcnt vmcnt(0) before barrier drains h stores

        if (tid == 0) {
            __hip_atomic_store(flg_g + (size_t)t * 16 + s, 1,
                               __ATOMIC_RELAXED, __HIP_MEMORY_SCOPE_AGENT);
        }
    }
}

// ---------------------------------------------------------------------------
// K2: logits[b][t][k] = b_out[k] + h_f(t).Wout[k][0:256] + h_b(t).Wout[k][256:512]
// thread per (b,t), b-minor so a wave's 64 lanes cover one t (better L2 reuse).
// ---------------------------------------------------------------------------
__global__ __launch_bounds__(256) void logits_kernel(
    const float* __restrict__ h_all, const float* __restrict__ W_out,
    const float* __restrict__ b_out, float* __restrict__ logits)
{
    int g = blockIdx.x * 256 + threadIdx.x;   // 0..32767
    int b = g & 63;
    int t = g >> 6;
    const float* hf = h_all + ((size_t)(t + 1) * B_SZ + b) * H_SZ;
    const float* hb = h_all + (size_t)513 * B_SZ * H_SZ + ((size_t)(512 - t) * B_SZ + b) * H_SZ;
    float acc[10];
#pragma unroll
    for (int k = 0; k < 10; ++k) acc[k] = b_out[k];
    for (int j = 0; j < 256; j += 4) {
        float4 a  = *(const float4*)(hf + j);
        float4 bb = *(const float4*)(hb + j);
#pragma unroll
        for (int k = 0; k < 10; ++k) {
            float4 w0 = *(const float4*)(W_out + (size_t)k * 512 + j);
            float4 w1 = *(const float4*)(W_out + (size_t)k * 512 + 256 + j);
            acc[k] += a.x * w0.x + a.y * w0.y + a.z * w0.z + a.w * w0.w
                    + bb.x * w1.x + bb.y * w1.y + bb.z * w1.z + bb.w * w1.w;
        }
    }
    float* lp = logits + ((size_t)b * 512 + t) * 10;
#pragma unroll
    for (int k = 0; k < 10; ++k) lp[k] = acc[k];
}

// ---------------------------------------------------------------------------
// K3: Viterbi per batch element. Block = 1 wave; trellis in lanes 0..9,
// backpointers + logits staged in LDS; serial backtrack from LDS.
// ---------------------------------------------------------------------------
__global__ __launch_bounds__(64) void viterbi_kernel(
    const float* __restrict__ logits, const float* __restrict__ trans,
    float* __restrict__ out)
{
    int b = blockIdx.x;
    int l = threadIdx.x;
    __shared__ __align__(16) float ll[512][10];
    __shared__ int   bp[512][10];
    __shared__ float path[512];

    const float* lp = logits + (size_t)b * 5120;
    for (int i = l; i < 5120; i += 64) ((float*)ll)[i] = lp[i];

    int j = (l < 10) ? l : 9;
    float tr[10];
#pragma unroll
    for (int i = 0; i < 10; ++i) tr[i] = trans[i * 10 + j];
    __syncthreads();

    float trellis = ll[0][j];
    for (int t = 1; t < 512; ++t) {
        float best = -3.0e30f; int arg = 0;
#pragma unroll
        for (int i = 0; i < 10; ++i) {
            float ti = __shfl(trellis, i, 64);
            float cand = ti + tr[i];
            bool gt = cand > best;           // strict > keeps first max (matches argmax)
            best = gt ? cand : best;
            arg  = gt ? i : arg;
        }
        if (l < 10) bp[t][l] = arg;
        trellis = ll[t][j] + best;
    }

    float best = -3.0e30f; int arg = 0;
#pragma unroll
    for (int i = 0; i < 10; ++i) {
        float ti = __shfl(trellis, i, 64);
        bool gt = ti > best;
        best = gt ? ti : best;
        arg  = gt ? i : arg;
    }
    __syncthreads();
    if (l == 0) {
        out[b] = best;
        int tag = arg;
        path[511] = (float)tag;
        for (int t2 = 510; t2 >= 0; --t2) {
            tag = bp[t2 + 1][tag];
            path[t2] = (float)tag;
        }
    }
    __syncthreads();
    float* po = out + 64 + (size_t)b * 512;
    for (int i = l; i < 512; i += 64) po[i] = path[i];
}

// ---------------------------------------------------------------------------
extern "C" void kernel_launch(void* const* d_in, const int* in_sizes, int n_in,
                              void* d_out, int out_size, void* d_ws, size_t ws_size,
                              hipStream_t stream)
{
    (void)in_sizes; (void)n_in; (void)out_size; (void)ws_size;
    const int*   sent  = (const int*)d_in[0];
    // d_in[1] = lengths (unused by the reference computation)
    const float* emb   = (const float*)d_in[2];
    const float* Wih_f = (const float*)d_in[3];
    const float* Whh_f = (const float*)d_in[4];
    const float* b_f   = (const float*)d_in[5];
    const float* Wih_b = (const float*)d_in[6];
    const float* Whh_b = (const float*)d_in[7];
    const float* b_b   = (const float*)d_in[8];
    const float* W_out = (const float*)d_in[9];
    const float* b_out = (const float*)d_in[10];
    const float* trans = (const float*)d_in[11];
    float* out = (float*)d_out;

    char* ws = (char*)d_ws;
    float* h_all = (float*)ws;                               // [2][513][64][256] f32
    const size_t h_bytes = (size_t)2 * 513 * B_SZ * H_SZ * 4;  // 67,239,936
    int*   flags  = (int*)(ws + h_bytes);                    // [16][512][16] i32 = 512 KB
    float* logits = (float*)(ws + h_bytes + 524288);         // [64][512][10] f32

    // zero initial h for both directions + all flags (ws is poisoned each call)
    hipMemsetAsync(h_all, 0, (size_t)B_SZ * H_SZ * 4, stream);
    hipMemsetAsync((char*)h_all + (size_t)513 * B_SZ * H_SZ * 4, 0,
                   (size_t)B_SZ * H_SZ * 4, stream);
    hipMemsetAsync(flags, 0, (size_t)16 * T_LEN * 16 * 4, stream);

    hipLaunchKernelGGL(lstm_kernel, dim3(256), dim3(512), 0, stream,
                       sent, emb, Wih_f, Whh_f, b_f, Wih_b, Whh_b, b_b, h_all, flags);
    hipLaunchKernelGGL(logits_kernel, dim3(128), dim3(256), 0, stream,
                       h_all, W_out, b_out, logits);
    hipLaunchKernelGGL(viterbi_kernel, dim3(64), dim3(64), 0, stream,
                       logits, trans, out);
}

// Round 4
// 5387.156 us; speedup vs baseline: 2.9770x; 1.5925x over previous
//
#include <hip/hip_runtime.h>
#include <cstdint>
#include <cstddef>

#define T_LEN 512
#define B_SZ  64
#define HDIM  256
#define PH_T  128   // timesteps per phase
#define NPH   4

__device__ __forceinline__ float sigf(float x) { return 1.0f / (1.0f + expf(-x)); }

__device__ __forceinline__ unsigned bf16rne(float f) {
    unsigned u = __float_as_uint(f);
    return (u + 0x7fffu + ((u >> 16) & 1u)) >> 16;
}

// ---------------------------------------------------------------------------
// K_P: pack Whh (f32 [1024][256]) -> bf16-pair dwords, lane-interleaved layout
// out dword index: (((d*16 + blk)*32 + kpc)*64 + lane)*4 + j
//   row = blk*64 + lane ; k = kpc*8 + j*2 (lo) / +1 (hi)
// so a wave's uint4 load at fixed (blk,kpc) is 1 KB fully coalesced.
// ---------------------------------------------------------------------------
__global__ void pack_whh(const float* __restrict__ Whh_f,
                         const float* __restrict__ Whh_b,
                         unsigned* __restrict__ outp)
{
    int o = blockIdx.x * 256 + threadIdx.x;        // 0..262143
    int j = o & 3, lane = (o >> 2) & 63, kpc = (o >> 8) & 31;
    int blk = (o >> 13) & 15, d = o >> 17;
    const float* W = d ? Whh_b : Whh_f;
    int row = blk * 64 + lane;
    int k0  = kpc * 8 + j * 2;
    unsigned lo = bf16rne(W[(size_t)row * 256 + k0]);
    unsigned hi = bf16rne(W[(size_t)row * 256 + k0 + 1]);
    outp[o] = lo | (hi << 16);
}

// ---------------------------------------------------------------------------
// K_G: input GEMM for one t-quarter. G[d][b][s][row] = Wih_d[row].x(b,t_in) + bias
// stored as bf16-pair dwords (rows 2j,2j+1). Fully parallel, f32 fma, VALU-bound.
// grid: 2048 blocks x 256: wg -> (d, rq row-quarter, tt t-subtile of 32, b)
// ---------------------------------------------------------------------------
__global__ void gemm_in(const int* __restrict__ sent, const float* __restrict__ emb,
                        const float* __restrict__ Wih_f, const float* __restrict__ b_f,
                        const float* __restrict__ Wih_b, const float* __restrict__ b_b,
                        unsigned* __restrict__ G, int q128)
{
    int wg = blockIdx.x;
    int d = wg & 1, rq = (wg >> 1) & 3, tt = (wg >> 3) & 3, b = wg >> 5;
    const float* Wih = d ? Wih_b : Wih_f;
    const float* bv  = d ? b_b   : b_f;
    int tid = threadIdx.x;
    __shared__ __align__(16) float x[32][256];   // 32 KB

    // stage x: thread (ti, seg) loads 32 floats of emb[token]
    int ti = tid >> 3, seg = tid & 7;
    int s_ti   = tt * 32 + ti;
    int tin_ti = d ? (511 - q128 - s_ti) : (q128 + s_ti);
    int tok = sent[b * 512 + tin_ti];
    {
        const float4* ep = (const float4*)(emb + (size_t)tok * 256 + seg * 32);
        float4* xp = (float4*)&x[ti][seg * 32];
#pragma unroll
        for (int i = 0; i < 8; ++i) xp[i] = ep[i];
    }
    __syncthreads();

    int row = rq * 256 + tid;
    float acc[32];
    float bias = bv[row];
#pragma unroll
    for (int t = 0; t < 32; ++t) acc[t] = bias;

    const float* wr = Wih + (size_t)row * 256;
    for (int k = 0; k < 256; k += 8) {
        float4 wa = *(const float4*)(wr + k);
        float4 wb = *(const float4*)(wr + k + 4);
#pragma unroll
        for (int t = 0; t < 32; ++t) {
            float4 xa = *(const float4*)&x[t][k];       // broadcast (uniform addr)
            float4 xb = *(const float4*)&x[t][k + 4];
            acc[t] += wa.x * xa.x + wa.y * xa.y + wa.z * xa.z + wa.w * xa.w
                    + wb.x * xb.x + wb.y * xb.y + wb.z * xb.z + wb.w * xb.w;
        }
    }

    // pack row pairs (even,odd lanes) -> dword, store
    size_t base = ((size_t)(d * 64 + b) * 128 + tt * 32) * 512;
#pragma unroll
    for (int t = 0; t < 32; ++t) {
        float part = __shfl_xor(acc[t], 1, 64);
        if (!(tid & 1)) {
            unsigned dw = bf16rne(acc[t]) | (bf16rne(part) << 16);
            G[base + (size_t)t * 512 + (row >> 1)] = dw;
        }
    }
}

// ---------------------------------------------------------------------------
// K_R: batch-partitioned recurrence, one t-quarter (128 steps). ZERO cross-WG
// communication. grid 64 x 512: wg -> (d, batch-pair). Thread owns rows
// (tid, tid+512); streams packed bf16 Whh from L2 (0.5 MB/step, coalesced),
// h state f32 in LDS ping-pong, c state f32 in register. Logit partials
// (h . W_out half) computed in the epilogue via shuffle reduce -> lh buffer.
// ---------------------------------------------------------------------------
__global__ __launch_bounds__(512) void lstm_rec(
    const unsigned* __restrict__ whh_p, const unsigned* __restrict__ G,
    const float* __restrict__ W_out, float* __restrict__ state,
    float* __restrict__ lh, int q128)
{
    int wg = blockIdx.x;            // 0..63
    int d = wg & 1, p = wg >> 1;
    int b0 = 2 * p;
    int tid = threadIdx.x;

    __shared__ __align__(16) float hbuf[2][2][256];  // ping-pong x b x h
    __shared__ __align__(16) float gsh[2][1024];
    __shared__ __align__(16) float wout[10][256];
    __shared__ float lred[8][10];

    for (int i = tid; i < 2560; i += 512) {
        int k = i >> 8, ih2 = i & 255;
        wout[k][ih2] = W_out[(size_t)k * 512 + d * 256 + ih2];
    }

    int bl = tid >> 8, ih = tid & 255;
    float c_reg  = state[(((size_t)d * 64 + b0 + bl) * 2 + 0) * 256 + ih];
    float h_last = state[(((size_t)d * 64 + b0 + bl) * 2 + 1) * 256 + ih];
    hbuf[0][bl][ih] = h_last;
    __syncthreads();

    const unsigned* w0p = whh_p + ((size_t)(d * 16 +      (tid >> 6)) * 32) * 256 + (tid & 63) * 4;
    const unsigned* w1p = whh_p + ((size_t)(d * 16 + 8 +  (tid >> 6)) * 32) * 256 + (tid & 63) * 4;
    const size_t gb0 = (size_t)(d * 64 + b0    ) * 128 * 512;
    const size_t gb1 = (size_t)(d * 64 + b0 + 1) * 128 * 512;
    const int r0h = tid >> 1, r1h = 256 + (tid >> 1);
    const bool hi_sel = tid & 1;
    const int lane = tid & 63;

    for (int t = 0; t < PH_T; ++t) {
        int cur = t & 1, nxt = cur ^ 1;
        // G loads issued early (latency hidden under the kpc loop)
        unsigned g00 = G[gb0 + (size_t)t * 512 + r0h];
        unsigned g01 = G[gb0 + (size_t)t * 512 + r1h];
        unsigned g10 = G[gb1 + (size_t)t * 512 + r0h];
        unsigned g11 = G[gb1 + (size_t)t * 512 + r1h];

        float a00 = 0.f, a01 = 0.f, a10 = 0.f, a11 = 0.f;
#pragma unroll 4
        for (int kpc = 0; kpc < 32; ++kpc) {
            uint4 w0 = *(const uint4*)(w0p + kpc * 256);
            uint4 w1 = *(const uint4*)(w1p + kpc * 256);
            float4 h0a = *(const float4*)&hbuf[cur][0][kpc * 8];
            float4 h0b = *(const float4*)&hbuf[cur][0][kpc * 8 + 4];
            float4 h1a = *(const float4*)&hbuf[cur][1][kpc * 8];
            float4 h1b = *(const float4*)&hbuf[cur][1][kpc * 8 + 4];
            float lo, hi;
            lo = __uint_as_float(w0.x << 16); hi = __uint_as_float(w0.x & 0xffff0000u);
            a00 += lo * h0a.x + hi * h0a.y;   a10 += lo * h1a.x + hi * h1a.y;
            lo = __uint_as_float(w0.y << 16); hi = __uint_as_float(w0.y & 0xffff0000u);
            a00 += lo * h0a.z + hi * h0a.w;   a10 += lo * h1a.z + hi * h1a.w;
            lo = __uint_as_float(w0.z << 16); hi = __uint_as_float(w0.z & 0xffff0000u);
            a00 += lo * h0b.x + hi * h0b.y;   a10 += lo * h1b.x + hi * h1b.y;
            lo = __uint_as_float(w0.w << 16); hi = __uint_as_float(w0.w & 0xffff0000u);
            a00 += lo * h0b.z + hi * h0b.w;   a10 += lo * h1b.z + hi * h1b.w;
            lo = __uint_as_float(w1.x << 16); hi = __uint_as_float(w1.x & 0xffff0000u);
            a01 += lo * h0a.x + hi * h0a.y;   a11 += lo * h1a.x + hi * h1a.y;
            lo = __uint_as_float(w1.y << 16); hi = __uint_as_float(w1.y & 0xffff0000u);
            a01 += lo * h0a.z + hi * h0a.w;   a11 += lo * h1a.z + hi * h1a.w;
            lo = __uint_as_float(w1.z << 16); hi = __uint_as_float(w1.z & 0xffff0000u);
            a01 += lo * h0b.x + hi * h0b.y;   a11 += lo * h1b.x + hi * h1b.y;
            lo = __uint_as_float(w1.w << 16); hi = __uint_as_float(w1.w & 0xffff0000u);
            a01 += lo * h0b.z + hi * h0b.w;   a11 += lo * h1b.z + hi * h1b.w;
        }
        // add input-gate contributions (bf16 pair, select own half)
        a00 += __uint_as_float(hi_sel ? (g00 & 0xffff0000u) : (g00 << 16));
        a01 += __uint_as_float(hi_sel ? (g01 & 0xffff0000u) : (g01 << 16));
        a10 += __uint_as_float(hi_sel ? (g10 & 0xffff0000u) : (g10 << 16));
        a11 += __uint_as_float(hi_sel ? (g11 & 0xffff0000u) : (g11 << 16));

        gsh[0][tid] = a00; gsh[0][tid + 512] = a01;
        gsh[1][tid] = a10; gsh[1][tid + 512] = a11;
        __syncthreads();                         // (A) gates ready

        float iv = gsh[bl][ih], fv = gsh[bl][256 + ih];
        float gg = gsh[bl][512 + ih], ov = gsh[bl][768 + ih];
        c_reg = sigf(fv) * c_reg + sigf(iv) * tanhf(gg);
        float hn = sigf(ov) * tanhf(c_reg);
        h_last = hn;
        hbuf[nxt][bl][ih] = hn;

        // logit partials: v_k = sum_ih hn * wout[k][ih] (wave butterfly)
        float keep = 0.f;
#pragma unroll
        for (int k = 0; k < 10; ++k) {
            float v = hn * wout[k][ih];
            v += __shfl_xor(v, 1, 64);  v += __shfl_xor(v, 2, 64);
            v += __shfl_xor(v, 4, 64);  v += __shfl_xor(v, 8, 64);
            v += __shfl_xor(v, 16, 64); v += __shfl_xor(v, 32, 64);
            if (lane == k) keep = v;
        }
        if (lane < 10) lred[tid >> 6][lane] = keep;
        __syncthreads();                         // (B) h(t+1) + lred ready

        if (tid < 20) {
            int bb = tid / 10, k = tid - bb * 10;
            float sum = lred[bb * 4 + 0][k] + lred[bb * 4 + 1][k]
                      + lred[bb * 4 + 2][k] + lred[bb * 4 + 3][k];
            int t_in = d ? (511 - q128 - t) : (q128 + t);
            lh[((size_t)(d * 64 + b0 + bb) * 512 + t_in) * 10 + k] = sum;
        }
    }

    state[(((size_t)d * 64 + b0 + bl) * 2 + 0) * 256 + ih] = c_reg;
    state[(((size_t)d * 64 + b0 + bl) * 2 + 1) * 256 + ih] = h_last;
}

// ---------------------------------------------------------------------------
// K_V: Viterbi per batch element; logits assembled from the two half-logit
// buffers + bias on load. Otherwise the proven R1 structure.
// ---------------------------------------------------------------------------
__global__ __launch_bounds__(64) void viterbi_kernel(
    const float* __restrict__ lh, const float* __restrict__ b_out,
    const float* __restrict__ trans, float* __restrict__ out)
{
    int b = blockIdx.x;
    int l = threadIdx.x;
    __shared__ __align__(16) float ll[512][10];
    __shared__ int   bp[512][10];
    __shared__ float path[512];
    __shared__ float bo[10];
    if (l < 10) bo[l] = b_out[l];
    __syncthreads();

    const float* l0 = lh + (size_t)b * 5120;
    const float* l1 = lh + (size_t)(64 + b) * 5120;
    for (int i = l; i < 5120; i += 64) {
        int j = i - (i / 10) * 10;
        ((float*)ll)[i] = l0[i] + l1[i] + bo[j];
    }

    int j = (l < 10) ? l : 9;
    float tr[10];
#pragma unroll
    for (int i = 0; i < 10; ++i) tr[i] = trans[i * 10 + j];
    __syncthreads();

    float trellis = ll[0][j];
    for (int t = 1; t < 512; ++t) {
        float best = -3.0e30f; int arg = 0;
#pragma unroll
        for (int i = 0; i < 10; ++i) {
            float ti = __shfl(trellis, i, 64);
            float cand = ti + tr[i];
            bool gt = cand > best;
            best = gt ? cand : best;
            arg  = gt ? i : arg;
        }
        if (l < 10) bp[t][l] = arg;
        trellis = ll[t][j] + best;
    }

    float best = -3.0e30f; int arg = 0;
#pragma unroll
    for (int i = 0; i < 10; ++i) {
        float ti = __shfl(trellis, i, 64);
        bool gt = ti > best;
        best = gt ? ti : best;
        arg  = gt ? i : arg;
    }
    __syncthreads();
    if (l == 0) {
        out[b] = best;
        int tag = arg;
        path[511] = (float)tag;
        for (int t2 = 510; t2 >= 0; --t2) {
            tag = bp[t2 + 1][tag];
            path[t2] = (float)tag;
        }
    }
    __syncthreads();
    float* po = out + 64 + (size_t)b * 512;
    for (int i = l; i < 512; i += 64) po[i] = path[i];
}

// ---------------------------------------------------------------------------
extern "C" void kernel_launch(void* const* d_in, const int* in_sizes, int n_in,
                              void* d_out, int out_size, void* d_ws, size_t ws_size,
                              hipStream_t stream)
{
    (void)in_sizes; (void)n_in; (void)out_size; (void)ws_size;
    const int*   sent  = (const int*)d_in[0];
    const float* emb   = (const float*)d_in[2];
    const float* Wih_f = (const float*)d_in[3];
    const float* Whh_f = (const float*)d_in[4];
    const float* b_f   = (const float*)d_in[5];
    const float* Wih_b = (const float*)d_in[6];
    const float* Whh_b = (const float*)d_in[7];
    const float* b_b   = (const float*)d_in[8];
    const float* W_out = (const float*)d_in[9];
    const float* b_out = (const float*)d_in[10];
    const float* trans = (const float*)d_in[11];
    float* out = (float*)d_out;

    char* ws = (char*)d_ws;
    unsigned* whh_p = (unsigned*)ws;                          // 262144 dw = 1 MB
    unsigned* G     = (unsigned*)(ws + (1u << 20));           // 8388608 dw = 33.55 MB
    float*    lh    = (float*)(ws + (1u << 20) + 33554432u);  // 2.62 MB
    float*    state = (float*)(ws + (1u << 20) + 33554432u + 2621440u + 4096u); // 0.26 MB

    // zero initial h/c state (ws is poisoned each call)
    hipMemsetAsync(state, 0, (size_t)2 * 64 * 2 * 256 * 4, stream);

    hipLaunchKernelGGL(pack_whh, dim3(1024), dim3(256), 0, stream,
                       Whh_f, Whh_b, whh_p);

    for (int q = 0; q < NPH; ++q) {
        hipLaunchKernelGGL(gemm_in, dim3(2048), dim3(256), 0, stream,
                           sent, emb, Wih_f, b_f, Wih_b, b_b, G, q * PH_T);
        hipLaunchKernelGGL(lstm_rec, dim3(64), dim3(512), 0, stream,
                           whh_p, G, W_out, state, lh, q * PH_T);
    }

    hipLaunchKernelGGL(viterbi_kernel, dim3(64), dim3(64), 0, stream,
                       lh, b_out, trans, out);
}

// Round 5
// 3522.366 us; speedup vs baseline: 4.5531x; 1.5294x over previous
//
#include <hip/hip_runtime.h>
#include <cstdint>
#include <cstddef>

#define T_LEN 512
#define B_SZ  64
#define PH_T  64            // timesteps per phase
#define NPH   8
#define PHG_DW (2u*64u*PH_T*512u)   // G dwords per phase = 4,194,304

typedef _Float16 half2_t __attribute__((ext_vector_type(2)));

__device__ __forceinline__ float sigf(float x) { return 1.0f / (1.0f + expf(-x)); }

__device__ __forceinline__ float dot2u(unsigned a, unsigned b, float c) {
#if defined(__has_builtin) && __has_builtin(__builtin_amdgcn_fdot2)
    return __builtin_amdgcn_fdot2(__builtin_bit_cast(half2_t, a),
                                  __builtin_bit_cast(half2_t, b), c, false);
#else
    union U { unsigned u; _Float16 h[2]; } ua, ub;
    ua.u = a; ub.u = b;
    return c + (float)ua.h[0] * (float)ub.h[0] + (float)ua.h[1] * (float)ub.h[1];
#endif
}

__device__ __forceinline__ unsigned pkh(float x, float y) {
    union { _Float16 h[2]; unsigned u; } r;
    r.h[0] = (_Float16)x; r.h[1] = (_Float16)y;
    return r.u;
}
__device__ __forceinline__ float halfsel(unsigned g, int hi) {
    union { unsigned u; _Float16 h[2]; } r; r.u = g;
    return (float)r.h[hi];
}

// ---------------------------------------------------------------------------
// K_P: pack all four weight matrices (f32 [1024][256]) into f16-pair dwords,
// lane-interleaved: idx = (((m*16+blk)*32 + kpc)*64 + lane)*4 + j
//   m: 0=Whh_f 1=Whh_b 2=Wih_f 3=Wih_b ; row = blk*64+lane ; k = kpc*8 + 2j(+1)
// A wave's uint4 load at fixed (m,blk,kpc) is 1 KB fully coalesced.
// ---------------------------------------------------------------------------
__global__ void pack_w(const float* __restrict__ Whh_f, const float* __restrict__ Whh_b,
                       const float* __restrict__ Wih_f, const float* __restrict__ Wih_b,
                       unsigned* __restrict__ pk)
{
    int o = blockIdx.x * 256 + threadIdx.x;     // 0..524287
    int j = o & 3, lane = (o >> 2) & 63, kpc = (o >> 8) & 31;
    int blk = (o >> 13) & 15, m = o >> 17;
    const float* W = (m == 0) ? Whh_f : (m == 1) ? Whh_b : (m == 2) ? Wih_f : Wih_b;
    int row = blk * 64 + lane, k0 = kpc * 8 + j * 2;
    pk[o] = pkh(W[(size_t)row * 256 + k0], W[(size_t)row * 256 + k0 + 1]);
}

// ---------------------------------------------------------------------------
// Fused phase kernel. grid 640 x 512, 64 KB LDS (caps residency at 2 blocks/CU
// so at most one gemm block shares a recurrence CU).
//   blocks 0..127   : recurrence for phase lq (1 chain (d,b) per block; skip lq<0)
//   blocks 128..639 : input GEMM producing G[gq&1] for phase gq (skip gq<0)
// Recurrence: thread owns gate rows (tid, tid+512); streams f16 Whh (coalesced
// uint4), h broadcast from LDS as f16 pairs, v_dot2_f32_f16 inner loop, c/h
// f32. Logit partials fused in epilogue. ZERO cross-WG communication.
// ---------------------------------------------------------------------------
struct LstmS {
    unsigned hbuf[2][128];     // f16-pair h, ping-pong
    float    gsh[1024];        // gate pre-activations
    float    wout[10][256];    // W_out half for this direction
    float    lred[4][16];      // per-wave logit partials
};
struct GemmS {
    unsigned x2[32][128];      // f16-pair x tile [t][k-pair]
};

__global__ __launch_bounds__(512) void fused_phase(
    const unsigned* __restrict__ pk, unsigned* __restrict__ G,
    const float* __restrict__ W_out, float* __restrict__ state,
    float* __restrict__ lh,
    const int* __restrict__ sent, const float* __restrict__ emb,
    const float* __restrict__ b_f, const float* __restrict__ b_b,
    int lq, int gq)
{
    __shared__ __align__(16) char smem[65536];
    const int tid = threadIdx.x;

    if (blockIdx.x < 128) {
        // ================= recurrence =================
        if (lq < 0) return;
        LstmS& S = *(LstmS*)smem;
        const int cid = blockIdx.x;
        const int d = cid & 1, b = cid >> 1;
        const int lane = tid & 63;

        for (int i = tid; i < 2560; i += 512) {
            int k = i >> 8, ih = i & 255;
            S.wout[k][ih] = W_out[(size_t)k * 512 + d * 256 + ih];
        }

        float cc = 0.f, hn = 0.f;
        if (tid < 256) {
            cc = state[((size_t)cid * 2 + 0) * 256 + tid];
            float hh = state[((size_t)cid * 2 + 1) * 256 + tid];
            float hp = __shfl_xor(hh, 1, 64);
            if (!(tid & 1)) S.hbuf[0][tid >> 1] = pkh(hh, hp);
        }
        __syncthreads();

        const unsigned* w0p = pk + (((size_t)d * 16 +     (tid >> 6)) * 32) * 256 + lane * 4;
        const unsigned* w1p = pk + (((size_t)d * 16 + 8 + (tid >> 6)) * 32) * 256 + lane * 4;
        const unsigned* Gc  = G + (size_t)(lq & 1) * PHG_DW
                                + ((size_t)(d * 64 + b)) * PH_T * 512;
        const int hi = tid & 1;

        for (int t = 0; t < PH_T; ++t) {
            const int cur = t & 1;
            unsigned g0 = Gc[(size_t)t * 512 +       (tid >> 1)];
            unsigned g1 = Gc[(size_t)t * 512 + 256 + (tid >> 1)];
            const unsigned* hc = S.hbuf[cur];

            float a0 = 0.f, a1 = 0.f;
#pragma unroll
            for (int kpc = 0; kpc < 32; ++kpc) {
                uint4 w0 = *(const uint4*)(w0p + kpc * 256);
                uint4 w1 = *(const uint4*)(w1p + kpc * 256);
                uint4 hp = *(const uint4*)&hc[kpc * 4];
                a0 = dot2u(w0.x, hp.x, a0); a0 = dot2u(w0.y, hp.y, a0);
                a0 = dot2u(w0.z, hp.z, a0); a0 = dot2u(w0.w, hp.w, a0);
                a1 = dot2u(w1.x, hp.x, a1); a1 = dot2u(w1.y, hp.y, a1);
                a1 = dot2u(w1.z, hp.z, a1); a1 = dot2u(w1.w, hp.w, a1);
            }
            a0 += halfsel(g0, hi);
            a1 += halfsel(g1, hi);
            S.gsh[tid]       = a0;
            S.gsh[tid + 512] = a1;
            __syncthreads();                 // (1) gates ready

            if (tid < 256) {
                float iv = S.gsh[tid],       fv = S.gsh[256 + tid];
                float gg = S.gsh[512 + tid], ov = S.gsh[768 + tid];
                cc = sigf(fv) * cc + sigf(iv) * tanhf(gg);
                hn = sigf(ov) * tanhf(cc);
                float hp = __shfl_xor(hn, 1, 64);
                if (!(tid & 1)) S.hbuf[cur ^ 1][tid >> 1] = pkh(hn, hp);
                // logit partials: reduce hn * wout[k][:] over this wave
                float keep = 0.f;
#pragma unroll
                for (int k = 0; k < 10; ++k) {
                    float v = hn * S.wout[k][tid];
                    v += __shfl_xor(v, 1, 64);  v += __shfl_xor(v, 2, 64);
                    v += __shfl_xor(v, 4, 64);  v += __shfl_xor(v, 8, 64);
                    v += __shfl_xor(v, 16, 64); v += __shfl_xor(v, 32, 64);
                    if (lane == k) keep = v;
                }
                if (lane < 10) S.lred[tid >> 6][lane] = keep;
            }
            __syncthreads();                 // (2) h(t+1) + lred ready

            if (tid < 10) {
                float sum = S.lred[0][tid] + S.lred[1][tid]
                          + S.lred[2][tid] + S.lred[3][tid];
                int tg = lq * PH_T + t;
                int t_in = d ? (511 - tg) : tg;
                lh[((size_t)(d * 64 + b) * 512 + t_in) * 10 + tid] = sum;
            }
        }

        if (tid < 256) {
            state[((size_t)cid * 2 + 0) * 256 + tid] = cc;
            state[((size_t)cid * 2 + 1) * 256 + tid] = hn;
        }
    } else {
        // ================= input GEMM for phase gq =================
        if (gq < 0) return;
        GemmS& S = *(GemmS*)smem;
        int gid = blockIdx.x - 128;                 // 0..511
        int d = gid & 1, rq = (gid >> 1) & 1, tt = (gid >> 2) & 1, b = gid >> 3;
        const float* bv = d ? b_b : b_f;

        // stage x tile (32 t x 256 k) as f16 pairs
        int ti = tid >> 4, seg = tid & 15;
        int tg  = gq * PH_T + tt * 32 + ti;
        int tin = d ? (511 - tg) : tg;
        int tok = sent[b * 512 + tin];
        {
            const float4* ep = (const float4*)(emb + (size_t)tok * 256 + seg * 16);
            float4 e0 = ep[0], e1 = ep[1], e2 = ep[2], e3 = ep[3];
            unsigned* xp = &S.x2[ti][seg * 8];
            xp[0] = pkh(e0.x, e0.y); xp[1] = pkh(e0.z, e0.w);
            xp[2] = pkh(e1.x, e1.y); xp[3] = pkh(e1.z, e1.w);
            xp[4] = pkh(e2.x, e2.y); xp[5] = pkh(e2.z, e2.w);
            xp[6] = pkh(e3.x, e3.y); xp[7] = pkh(e3.z, e3.w);
        }
        __syncthreads();

        int row = rq * 512 + tid;
        int blk = row >> 6, lane = tid & 63;
        const unsigned* wp = pk + (((size_t)(2 + d) * 16 + blk) * 32) * 256 + lane * 4;

        float bias = bv[row];
        float acc[32];
#pragma unroll
        for (int t = 0; t < 32; ++t) acc[t] = bias;

        for (int kpc = 0; kpc < 32; ++kpc) {
            uint4 w = *(const uint4*)(wp + kpc * 256);
#pragma unroll
            for (int t = 0; t < 32; ++t) {
                uint4 xv = *(const uint4*)&S.x2[t][kpc * 4];
                acc[t] = dot2u(w.x, xv.x, acc[t]);
                acc[t] = dot2u(w.y, xv.y, acc[t]);
                acc[t] = dot2u(w.z, xv.z, acc[t]);
                acc[t] = dot2u(w.w, xv.w, acc[t]);
            }
        }

        unsigned* Gg = G + (size_t)(gq & 1) * PHG_DW;
        size_t gbase = ((size_t)(d * 64 + b) * PH_T + tt * 32) * 512;
#pragma unroll
        for (int t = 0; t < 32; ++t) {
            float part = __shfl_xor(acc[t], 1, 64);
            if (!(tid & 1))
                Gg[gbase + (size_t)t * 512 + (row >> 1)] = pkh(acc[t], part);
        }
    }
}

// ---------------------------------------------------------------------------
// K_V: Viterbi per batch element (proven R4 structure).
// ---------------------------------------------------------------------------
__global__ __launch_bounds__(64) void viterbi_kernel(
    const float* __restrict__ lh, const float* __restrict__ b_out,
    const float* __restrict__ trans, float* __restrict__ out)
{
    int b = blockIdx.x;
    int l = threadIdx.x;
    __shared__ __align__(16) float ll[512][10];
    __shared__ int   bp[512][10];
    __shared__ float path[512];
    __shared__ float bo[10];
    if (l < 10) bo[l] = b_out[l];
    __syncthreads();

    const float* l0 = lh + (size_t)b * 5120;
    const float* l1 = lh + (size_t)(64 + b) * 5120;
    for (int i = l; i < 5120; i += 64) {
        int j = i - (i / 10) * 10;
        ((float*)ll)[i] = l0[i] + l1[i] + bo[j];
    }

    int j = (l < 10) ? l : 9;
    float tr[10];
#pragma unroll
    for (int i = 0; i < 10; ++i) tr[i] = trans[i * 10 + j];
    __syncthreads();

    float trellis = ll[0][j];
    for (int t = 1; t < 512; ++t) {
        float best = -3.0e30f; int arg = 0;
#pragma unroll
        for (int i = 0; i < 10; ++i) {
            float ti = __shfl(trellis, i, 64);
            float cand = ti + tr[i];
            bool gt = cand > best;
            best = gt ? cand : best;
            arg  = gt ? i : arg;
        }
        if (l < 10) bp[t][l] = arg;
        trellis = ll[t][j] + best;
    }

    float best = -3.0e30f; int arg = 0;
#pragma unroll
    for (int i = 0; i < 10; ++i) {
        float ti = __shfl(trellis, i, 64);
        bool gt = ti > best;
        best = gt ? ti : best;
        arg  = gt ? i : arg;
    }
    __syncthreads();
    if (l == 0) {
        out[b] = best;
        int tag = arg;
        path[511] = (float)tag;
        for (int t2 = 510; t2 >= 0; --t2) {
            tag = bp[t2 + 1][tag];
            path[t2] = (float)tag;
        }
    }
    __syncthreads();
    float* po = out + 64 + (size_t)b * 512;
    for (int i = l; i < 512; i += 64) po[i] = path[i];
}

// ---------------------------------------------------------------------------
extern "C" void kernel_launch(void* const* d_in, const int* in_sizes, int n_in,
                              void* d_out, int out_size, void* d_ws, size_t ws_size,
                              hipStream_t stream)
{
    (void)in_sizes; (void)n_in; (void)out_size; (void)ws_size;
    const int*   sent  = (const int*)d_in[0];
    const float* emb   = (const float*)d_in[2];
    const float* Wih_f = (const float*)d_in[3];
    const float* Whh_f = (const float*)d_in[4];
    const float* b_f   = (const float*)d_in[5];
    const float* Wih_b = (const float*)d_in[6];
    const float* Whh_b = (const float*)d_in[7];
    const float* b_b   = (const float*)d_in[8];
    const float* W_out = (const float*)d_in[9];
    const float* b_out = (const float*)d_in[10];
    const float* trans = (const float*)d_in[11];
    float* out = (float*)d_out;

    char* ws = (char*)d_ws;
    unsigned* pk    = (unsigned*)ws;                              // 2 MB
    unsigned* G     = (unsigned*)(ws + 2097152u);                 // 2 x 16.78 MB
    float*    lh    = (float*)(ws + 2097152u + 33554432u);        // 2.62 MB
    float*    state = (float*)(ws + 2097152u + 33554432u + 2621440u);  // 256 KB

    hipMemsetAsync(state, 0, (size_t)2 * 64 * 2 * 256 * 4, stream);

    hipLaunchKernelGGL(pack_w, dim3(2048), dim3(256), 0, stream,
                       Whh_f, Whh_b, Wih_f, Wih_b, pk);

    // pipeline: launch i builds G(i) while running recurrence phase i-1
    hipLaunchKernelGGL(fused_phase, dim3(640), dim3(512), 0, stream,
                       pk, G, W_out, state, lh, sent, emb, b_f, b_b, -1, 0);
    for (int q = 0; q < NPH; ++q) {
        hipLaunchKernelGGL(fused_phase, dim3(640), dim3(512), 0, stream,
                           pk, G, W_out, state, lh, sent, emb, b_f, b_b,
                           q, (q < NPH - 1) ? (q + 1) : -1);
    }

    hipLaunchKernelGGL(viterbi_kernel, dim3(64), dim3(64), 0, stream,
                       lh, b_out, trans, out);
}

// Round 6
// 1828.823 us; speedup vs baseline: 8.7694x; 1.9260x over previous
//
#include <hip/hip_runtime.h>
#include <cstdint>
#include <cstddef>

#define T_LEN 512
#define B_SZ  64
#define PH_T  64            // timesteps per phase
#define NPH   8
#define PHG_DW (2u*64u*PH_T*512u)   // G dwords per phase = 4,194,304

typedef _Float16 half2_t __attribute__((ext_vector_type(2)));

__device__ __forceinline__ float sigf(float x) { return 1.0f / (1.0f + expf(-x)); }

__device__ __forceinline__ float dot2u(unsigned a, unsigned b, float c) {
#if defined(__has_builtin) && __has_builtin(__builtin_amdgcn_fdot2)
    return __builtin_amdgcn_fdot2(__builtin_bit_cast(half2_t, a),
                                  __builtin_bit_cast(half2_t, b), c, false);
#else
    union U { unsigned u; _Float16 h[2]; } ua, ub;
    ua.u = a; ub.u = b;
    return c + (float)ua.h[0] * (float)ub.h[0] + (float)ua.h[1] * (float)ub.h[1];
#endif
}

__device__ __forceinline__ unsigned pkh(float x, float y) {
    union { _Float16 h[2]; unsigned u; } r;
    r.h[0] = (_Float16)x; r.h[1] = (_Float16)y;
    return r.u;
}
__device__ __forceinline__ float halfsel(unsigned g, int hi) {
    union { unsigned u; _Float16 h[2]; } r; r.u = g;
    return (float)r.h[hi];
}

// ---------------------------------------------------------------------------
// K_P: pack all four weight matrices (f32 [1024][256]) into f16-pair dwords,
// lane-interleaved: idx = (((m*16+blk)*32 + kpc)*64 + lane)*4 + j
//   m: 0=Whh_f 1=Whh_b 2=Wih_f 3=Wih_b ; row = blk*64+lane ; k = kpc*8 + 2j(+1)
// ---------------------------------------------------------------------------
__global__ void pack_w(const float* __restrict__ Whh_f, const float* __restrict__ Whh_b,
                       const float* __restrict__ Wih_f, const float* __restrict__ Wih_b,
                       unsigned* __restrict__ pk)
{
    int o = blockIdx.x * 256 + threadIdx.x;     // 0..524287
    int j = o & 3, lane = (o >> 2) & 63, kpc = (o >> 8) & 31;
    int blk = (o >> 13) & 15, m = o >> 17;
    const float* W = (m == 0) ? Whh_f : (m == 1) ? Whh_b : (m == 2) ? Wih_f : Wih_b;
    int row = blk * 64 + lane, k0 = kpc * 8 + j * 2;
    pk[o] = pkh(W[(size_t)row * 256 + k0], W[(size_t)row * 256 + k0 + 1]);
}

// ---------------------------------------------------------------------------
// Fused phase kernel. grid 640 x 512. Static LDS ~143 KB -> 1 block/CU.
//   blocks 0..127   : recurrence for phase lq (1 chain (d,b) per block)
//   blocks 128..639 : input GEMM producing G[gq&1] for phase gq
// Recurrence weight residency per step (512 KB f16 Whh per direction):
//   kpc  0..15 : VGPR-resident (128 regs/thread, loaded once per phase)
//   kpc 16..23 : LDS-resident (128 KB, staged once per phase)
//   kpc 24..31 : streamed from L2 (128 KB/step), issued early / consumed last
// ZERO cross-WG communication.
// ---------------------------------------------------------------------------
struct LstmS {
    uint4    wl[2][8][512];    // LDS-cached weight chunks (128 KB)
    unsigned hbuf[2][128];     // f16-pair h, ping-pong
    float    gsh[1024];        // gate pre-activations
    float    wout[10][256];    // W_out half for this direction
    float    lred[4][16];      // per-wave logit partials
};
struct GemmS {
    unsigned x2[32][128];      // f16-pair x tile [t][k-pair]
};

__global__ __launch_bounds__(512, 2) void fused_phase(
    const unsigned* __restrict__ pk, unsigned* __restrict__ G,
    const float* __restrict__ W_out, float* __restrict__ state,
    float* __restrict__ lh,
    const int* __restrict__ sent, const float* __restrict__ emb,
    const float* __restrict__ b_f, const float* __restrict__ b_b,
    int lq, int gq)
{
    __shared__ __align__(16) char smem[147456];
    const int tid = threadIdx.x;

    if (blockIdx.x < 128) {
        // ================= recurrence =================
        if (lq < 0) return;
        LstmS& S = *(LstmS*)smem;
        const int cid = blockIdx.x;
        const int d = cid & 1, b = cid >> 1;
        const int lane = tid & 63;

        for (int i = tid; i < 2560; i += 512) {
            int k = i >> 8, ih = i & 255;
            S.wout[k][ih] = W_out[(size_t)k * 512 + d * 256 + ih];
        }

        float cc = 0.f, hn = 0.f;
        if (tid < 256) {
            cc = state[((size_t)cid * 2 + 0) * 256 + tid];
            float hh = state[((size_t)cid * 2 + 1) * 256 + tid];
            float hp = __shfl_xor(hh, 1, 64);
            if (!(tid & 1)) S.hbuf[0][tid >> 1] = pkh(hh, hp);
        }

        const unsigned* w0p = pk + (((size_t)d * 16 +     (tid >> 6)) * 32) * 256 + lane * 4;
        const unsigned* w1p = pk + (((size_t)d * 16 + 8 + (tid >> 6)) * 32) * 256 + lane * 4;
        const unsigned* Gc  = G + (size_t)(lq & 1) * PHG_DW
                                + ((size_t)(d * 64 + b)) * PH_T * 512;
        const int hi = tid & 1;

        // ---- VGPR-resident weights: kpc 0..15 (128 VGPRs) ----
        uint4 wr0[16], wr1[16];
#pragma unroll
        for (int k = 0; k < 16; ++k) {
            wr0[k] = *(const uint4*)(w0p + k * 256);
            wr1[k] = *(const uint4*)(w1p + k * 256);
        }
        // ---- LDS-resident weights: kpc 16..23 (128 KB) ----
#pragma unroll
        for (int k = 0; k < 8; ++k) {
            S.wl[0][k][tid] = *(const uint4*)(w0p + (16 + k) * 256);
            S.wl[1][k][tid] = *(const uint4*)(w1p + (16 + k) * 256);
        }
        __syncthreads();

        for (int t = 0; t < PH_T; ++t) {
            const int cur = t & 1;
            // ---- streamed weights: kpc 24..31, issued first ----
            uint4 s0[8], s1[8];
#pragma unroll
            for (int k = 0; k < 8; ++k) {
                s0[k] = *(const uint4*)(w0p + (24 + k) * 256);
                s1[k] = *(const uint4*)(w1p + (24 + k) * 256);
            }
            unsigned g0 = Gc[(size_t)t * 512 +       (tid >> 1)];
            unsigned g1 = Gc[(size_t)t * 512 + 256 + (tid >> 1)];
            const unsigned* hc = S.hbuf[cur];

            float a0 = 0.f, a1 = 0.f;
            // VGPR-cached chunks
#pragma unroll
            for (int k = 0; k < 16; ++k) {
                uint4 hp = *(const uint4*)&hc[k * 4];
                a0 = dot2u(wr0[k].x, hp.x, a0); a0 = dot2u(wr0[k].y, hp.y, a0);
                a0 = dot2u(wr0[k].z, hp.z, a0); a0 = dot2u(wr0[k].w, hp.w, a0);
                a1 = dot2u(wr1[k].x, hp.x, a1); a1 = dot2u(wr1[k].y, hp.y, a1);
                a1 = dot2u(wr1[k].z, hp.z, a1); a1 = dot2u(wr1[k].w, hp.w, a1);
            }
            // LDS-cached chunks
#pragma unroll
            for (int k = 0; k < 8; ++k) {
                uint4 hp = *(const uint4*)&hc[(16 + k) * 4];
                uint4 w0 = S.wl[0][k][tid];
                uint4 w1 = S.wl[1][k][tid];
                a0 = dot2u(w0.x, hp.x, a0); a0 = dot2u(w0.y, hp.y, a0);
                a0 = dot2u(w0.z, hp.z, a0); a0 = dot2u(w0.w, hp.w, a0);
                a1 = dot2u(w1.x, hp.x, a1); a1 = dot2u(w1.y, hp.y, a1);
                a1 = dot2u(w1.z, hp.z, a1); a1 = dot2u(w1.w, hp.w, a1);
            }
            // streamed chunks (loads have had the whole step to land)
#pragma unroll
            for (int k = 0; k < 8; ++k) {
                uint4 hp = *(const uint4*)&hc[(24 + k) * 4];
                a0 = dot2u(s0[k].x, hp.x, a0); a0 = dot2u(s0[k].y, hp.y, a0);
                a0 = dot2u(s0[k].z, hp.z, a0); a0 = dot2u(s0[k].w, hp.w, a0);
                a1 = dot2u(s1[k].x, hp.x, a1); a1 = dot2u(s1[k].y, hp.y, a1);
                a1 = dot2u(s1[k].z, hp.z, a1); a1 = dot2u(s1[k].w, hp.w, a1);
            }
            a0 += halfsel(g0, hi);
            a1 += halfsel(g1, hi);
            S.gsh[tid]       = a0;
            S.gsh[tid + 512] = a1;
            __syncthreads();                 // (1) gates ready

            if (tid < 256) {
                float iv = S.gsh[tid],       fv = S.gsh[256 + tid];
                float gg = S.gsh[512 + tid], ov = S.gsh[768 + tid];
                cc = sigf(fv) * cc + sigf(iv) * tanhf(gg);
                hn = sigf(ov) * tanhf(cc);
                float hp = __shfl_xor(hn, 1, 64);
                if (!(tid & 1)) S.hbuf[cur ^ 1][tid >> 1] = pkh(hn, hp);
                // logit partials: reduce hn * wout[k][:] over this wave
                float keep = 0.f;
#pragma unroll
                for (int k = 0; k < 10; ++k) {
                    float v = hn * S.wout[k][tid];
                    v += __shfl_xor(v, 1, 64);  v += __shfl_xor(v, 2, 64);
                    v += __shfl_xor(v, 4, 64);  v += __shfl_xor(v, 8, 64);
                    v += __shfl_xor(v, 16, 64); v += __shfl_xor(v, 32, 64);
                    if (lane == k) keep = v;
                }
                if (lane < 10) S.lred[tid >> 6][lane] = keep;
            }
            __syncthreads();                 // (2) h(t+1) + lred ready

            if (tid < 10) {
                float sum = S.lred[0][tid] + S.lred[1][tid]
                          + S.lred[2][tid] + S.lred[3][tid];
                int tg = lq * PH_T + t;
                int t_in = d ? (511 - tg) : tg;
                lh[((size_t)(d * 64 + b) * 512 + t_in) * 10 + tid] = sum;
            }
        }

        if (tid < 256) {
            state[((size_t)cid * 2 + 0) * 256 + tid] = cc;
            state[((size_t)cid * 2 + 1) * 256 + tid] = hn;
        }
    } else {
        // ================= input GEMM for phase gq =================
        if (gq < 0) return;
        GemmS& S = *(GemmS*)smem;
        int gid = blockIdx.x - 128;                 // 0..511
        int d = gid & 1, rq = (gid >> 1) & 1, tt = (gid >> 2) & 1, b = gid >> 3;
        const float* bv = d ? b_b : b_f;

        // stage x tile (32 t x 256 k) as f16 pairs
        int ti = tid >> 4, seg = tid & 15;
        int tg  = gq * PH_T + tt * 32 + ti;
        int tin = d ? (511 - tg) : tg;
        int tok = sent[b * 512 + tin];
        {
            const float4* ep = (const float4*)(emb + (size_t)tok * 256 + seg * 16);
            float4 e0 = ep[0], e1 = ep[1], e2 = ep[2], e3 = ep[3];
            unsigned* xp = &S.x2[ti][seg * 8];
            xp[0] = pkh(e0.x, e0.y); xp[1] = pkh(e0.z, e0.w);
            xp[2] = pkh(e1.x, e1.y); xp[3] = pkh(e1.z, e1.w);
            xp[4] = pkh(e2.x, e2.y); xp[5] = pkh(e2.z, e2.w);
            xp[6] = pkh(e3.x, e3.y); xp[7] = pkh(e3.z, e3.w);
        }
        __syncthreads();

        int row = rq * 512 + tid;
        int blk = row >> 6, lane = tid & 63;
        const unsigned* wp = pk + (((size_t)(2 + d) * 16 + blk) * 32) * 256 + lane * 4;

        float bias = bv[row];
        float acc[32];
#pragma unroll
        for (int t = 0; t < 32; ++t) acc[t] = bias;

        for (int kpc = 0; kpc < 32; ++kpc) {
            uint4 w = *(const uint4*)(wp + kpc * 256);
#pragma unroll
            for (int t = 0; t < 32; ++t) {
                uint4 xv = *(const uint4*)&S.x2[t][kpc * 4];
                acc[t] = dot2u(w.x, xv.x, acc[t]);
                acc[t] = dot2u(w.y, xv.y, acc[t]);
                acc[t] = dot2u(w.z, xv.z, acc[t]);
                acc[t] = dot2u(w.w, xv.w, acc[t]);
            }
        }

        unsigned* Gg = G + (size_t)(gq & 1) * PHG_DW;
        size_t gbase = ((size_t)(d * 64 + b) * PH_T + tt * 32) * 512;
#pragma unroll
        for (int t = 0; t < 32; ++t) {
            float part = __shfl_xor(acc[t], 1, 64);
            if (!(tid & 1))
                Gg[gbase + (size_t)t * 512 + (row >> 1)] = pkh(acc[t], part);
        }
    }
}

// ---------------------------------------------------------------------------
// K_V: Viterbi per batch element (proven structure).
// ---------------------------------------------------------------------------
__global__ __launch_bounds__(64) void viterbi_kernel(
    const float* __restrict__ lh, const float* __restrict__ b_out,
    const float* __restrict__ trans, float* __restrict__ out)
{
    int b = blockIdx.x;
    int l = threadIdx.x;
    __shared__ __align__(16) float ll[512][10];
    __shared__ int   bp[512][10];
    __shared__ float path[512];
    __shared__ float bo[10];
    if (l < 10) bo[l] = b_out[l];
    __syncthreads();

    const float* l0 = lh + (size_t)b * 5120;
    const float* l1 = lh + (size_t)(64 + b) * 5120;
    for (int i = l; i < 5120; i += 64) {
        int j = i - (i / 10) * 10;
        ((float*)ll)[i] = l0[i] + l1[i] + bo[j];
    }

    int j = (l < 10) ? l : 9;
    float tr[10];
#pragma unroll
    for (int i = 0; i < 10; ++i) tr[i] = trans[i * 10 + j];
    __syncthreads();

    float trellis = ll[0][j];
    for (int t = 1; t < 512; ++t) {
        float best = -3.0e30f; int arg = 0;
#pragma unroll
        for (int i = 0; i < 10; ++i) {
            float ti = __shfl(trellis, i, 64);
            float cand = ti + tr[i];
            bool gt = cand > best;
            best = gt ? cand : best;
            arg  = gt ? i : arg;
        }
        if (l < 10) bp[t][l] = arg;
        trellis = ll[t][j] + best;
    }

    float best = -3.0e30f; int arg = 0;
#pragma unroll
    for (int i = 0; i < 10; ++i) {
        float ti = __shfl(trellis, i, 64);
        bool gt = ti > best;
        best = gt ? ti : best;
        arg  = gt ? i : arg;
    }
    __syncthreads();
    if (l == 0) {
        out[b] = best;
        int tag = arg;
        path[511] = (float)tag;
        for (int t2 = 510; t2 >= 0; --t2) {
            tag = bp[t2 + 1][tag];
            path[t2] = (float)tag;
        }
    }
    __syncthreads();
    float* po = out + 64 + (size_t)b * 512;
    for (int i = l; i < 512; i += 64) po[i] = path[i];
}

// ---------------------------------------------------------------------------
extern "C" void kernel_launch(void* const* d_in, const int* in_sizes, int n_in,
                              void* d_out, int out_size, void* d_ws, size_t ws_size,
                              hipStream_t stream)
{
    (void)in_sizes; (void)n_in; (void)out_size; (void)ws_size;
    const int*   sent  = (const int*)d_in[0];
    const float* emb   = (const float*)d_in[2];
    const float* Wih_f = (const float*)d_in[3];
    const float* Whh_f = (const float*)d_in[4];
    const float* b_f   = (const float*)d_in[5];
    const float* Wih_b = (const float*)d_in[6];
    const float* Whh_b = (const float*)d_in[7];
    const float* b_b   = (const float*)d_in[8];
    const float* W_out = (const float*)d_in[9];
    const float* b_out = (const float*)d_in[10];
    const float* trans = (const float*)d_in[11];
    float* out = (float*)d_out;

    char* ws = (char*)d_ws;
    unsigned* pk    = (unsigned*)ws;                              // 2 MB
    unsigned* G     = (unsigned*)(ws + 2097152u);                 // 2 x 16.78 MB
    float*    lh    = (float*)(ws + 2097152u + 33554432u);        // 2.62 MB
    float*    state = (float*)(ws + 2097152u + 33554432u + 2621440u);  // 256 KB

    hipMemsetAsync(state, 0, (size_t)2 * 64 * 2 * 256 * 4, stream);

    hipLaunchKernelGGL(pack_w, dim3(2048), dim3(256), 0, stream,
                       Whh_f, Whh_b, Wih_f, Wih_b, pk);

    // pipeline: launch i builds G(i) while running recurrence phase i-1
    hipLaunchKernelGGL(fused_phase, dim3(640), dim3(512), 0, stream,
                       pk, G, W_out, state, lh, sent, emb, b_f, b_b, -1, 0);
    for (int q = 0; q < NPH; ++q) {
        hipLaunchKernelGGL(fused_phase, dim3(640), dim3(512), 0, stream,
                           pk, G, W_out, state, lh, sent, emb, b_f, b_b,
                           q, (q < NPH - 1) ? (q + 1) : -1);
    }

    hipLaunchKernelGGL(viterbi_kernel, dim3(64), dim3(64), 0, stream,
                       lh, b_out, trans, out);
}